// Round 3
// baseline (55509.491 us; speedup 1.0000x reference)
//
#include <hip/hip_runtime.h>

typedef unsigned short u16;
typedef __attribute__((ext_vector_type(8))) short short8;
typedef __attribute__((ext_vector_type(4))) float f32x4;

#define B_ 2048
#define T_ 64
#define I_ 64
#define H_ 1024
#define G_ 4096
#define NBLK 768

__device__ __forceinline__ float bf2f(u16 v) {
  union { float f; unsigned u; } x; x.u = ((unsigned)v) << 16; return x.f;
}
__device__ __forceinline__ u16 f2bf(float f) {
  union { float f; unsigned u; } x; x.f = f;
  unsigned r = x.u + 0x7fffu + ((x.u >> 16) & 1u);
  return (u16)(r >> 16);
}
__device__ __forceinline__ float sigm(float x) { return 1.0f / (1.0f + __expf(-x)); }
__device__ __forceinline__ float tanh_(float x) { return 1.0f - 2.0f / (__expf(2.0f * x) + 1.0f); }

__device__ __forceinline__ void async_copy16(const u16* g, u16* l) {
  __builtin_amdgcn_global_load_lds((__attribute__((address_space(1))) void*)(void*)g,
                                   (__attribute__((address_space(3))) void*)l, 16, 0, 0);
}

// -------------------- setup kernels --------------------

__global__ void k_transpose_x(const float* __restrict__ x, u16* __restrict__ xT) {
  int idx = blockIdx.x * 256 + threadIdx.x;
  if (idx >= B_ * T_ * I_) return;
  int i = idx & 63;
  int t = (idx >> 6) & 63;
  int b = idx >> 12;
  xT[((size_t)t * B_ + b) * I_ + i] = f2bf(x[idx]);
}

// Coalesced build of BT [4096][K] bf16 via LDS transpose.
// Row n' = 4*unit + gate; source col j = gate*1024 + unit; k<K0 from U else W.
__global__ void k_build_bt2(const float* __restrict__ U, const float* __restrict__ W,
                            u16* __restrict__ BT, int K0, int K) {
  __shared__ u16 tile[64][65];
  int k0 = blockIdx.x << 6, j0 = blockIdx.y << 6;
  int tx = threadIdx.x & 63, ty = threadIdx.x >> 6;
#pragma unroll 4
  for (int it = 0; it < 16; ++it) {
    int k = k0 + (it << 2) + ty;
    float v = (k < K0) ? U[(size_t)k * G_ + j0 + tx]
                       : W[(size_t)(k - K0) * G_ + j0 + tx];
    tile[tx][(it << 2) + ty] = f2bf(v);
  }
  __syncthreads();
#pragma unroll 4
  for (int it = 0; it < 16; ++it) {
    int j = j0 + (it << 2) + ty;
    int n = ((j & 1023) << 2) | (j >> 10);
    BT[(size_t)n * K + k0 + tx] = tile[(it << 2) + ty][tx];
  }
}

__global__ void k_build_bias(const float* __restrict__ b1, const float* __restrict__ b2,
                             const float* __restrict__ bd1, const float* __restrict__ bd2,
                             const float* __restrict__ d1W,
                             float* __restrict__ p1, float* __restrict__ p2,
                             float* __restrict__ pd1, float* __restrict__ pd2,
                             float* __restrict__ pd1W) {
  int n = blockIdx.x * 256 + threadIdx.x;
  if (n >= G_) return;
  int j = (n & 3) * 1024 + (n >> 2);
  p1[n] = b1[j]; p2[n] = b2[j]; pd1[n] = bd1[j]; pd2[n] = bd2[j];
  pd1W[n] = d1W[j];
}

// -------------------- params --------------------

struct Params {
  const u16* xT;
  const u16 *BT1, *BT2, *BTd1, *BTd2;
  const float *pb1, *pb2, *pbd1, *pbd2, *pd1W;
  float *c1, *c2, *cd1, *cd2;
  u16 *h1a, *h1b, *h2a, *h2b, *hd1a, *hd1b, *hd2a, *hd2b;
  float *c3, *h3;
  const float *g3W, *g3U, *g3b, *doW, *dob;
  float *gen, *disc;
  int* bcnt;
};

// -------------------- fused GEMM + LSTM cell (device body) --------------------

__device__ __forceinline__ void gemm_body(
    u16* smem, int bid,
    const u16* __restrict__ A0, int lda0, int kt0,
    const u16* __restrict__ A1, int lda1, int kt1,
    const u16* __restrict__ BT, int ldb,
    const float* __restrict__ biasp,
    const float* __restrict__ evec,
    const float* __restrict__ escal, int estride,
    float* __restrict__ cst, u16* __restrict__ hout) {
  const int tid = threadIdx.x;
  const int lane = tid & 63;
  const int w = tid >> 6;
  const int m0 = (bid & 15) << 7;
  const int n0 = (bid >> 4) << 7;
  const int KT = kt0 + kt1;

  const int r_ = tid >> 3, c_ = tid & 7;
  const u16* pA0[4]; const u16* pA1[4]; const u16* pB[4];
#pragma unroll
  for (int s = 0; s < 4; ++s) {
    int rs = (s << 5) + r_;
    int ch = (c_ ^ (rs & 7)) << 3;
    pA0[s] = A0 + (size_t)(m0 + rs) * lda0 + ch;
    pA1[s] = A1 ? (A1 + (size_t)(m0 + rs) * lda1 + ch) : pA0[s];
    pB[s] = BT + (size_t)(n0 + rs) * ldb + ch;
  }
  u16* ldsA = smem + (w << 9);
  u16* ldsB = smem + 8192 + (w << 9);

  f32x4 acc[4][4];
#pragma unroll
  for (int i = 0; i < 4; ++i)
#pragma unroll
    for (int j = 0; j < 4; ++j) acc[i][j] = (f32x4){0.f, 0.f, 0.f, 0.f};

  const int wm = (w >> 1) << 6, wn = (w & 1) << 6;
  const int q = lane >> 4, l15 = lane & 15, l7 = lane & 7;
  int aoffr[4], boffr[4];
#pragma unroll
  for (int i = 0; i < 4; ++i) {
    aoffr[i] = (wm + (i << 4) + l15) << 6;
    boffr[i] = 8192 + ((wn + (i << 4) + l15) << 6);
  }

  for (int kt = 0; kt < KT; ++kt) {
    __syncthreads();
    bool seg0 = (kt < kt0);
#pragma unroll
    for (int s = 0; s < 4; ++s) {
      const u16* ga = seg0 ? (pA0[s] + (size_t)kt * 64)
                           : (pA1[s] + (size_t)(kt - kt0) * 64);
      async_copy16(ga, ldsA + (s << 11));
      async_copy16(pB[s] + (size_t)kt * 64, ldsB + (s << 11));
    }
    __syncthreads();
#pragma unroll
    for (int ks = 0; ks < 2; ++ks) {
      const int sw = ((((ks << 2) + q) ^ l7) << 3);
      short8 af[4], bfr[4];
#pragma unroll
      for (int i = 0; i < 4; ++i) {
        af[i] = *(const short8*)&smem[aoffr[i] + sw];
        bfr[i] = *(const short8*)&smem[boffr[i] + sw];
      }
#pragma unroll
      for (int i = 0; i < 4; ++i)
#pragma unroll
        for (int j = 0; j < 4; ++j)
          acc[i][j] = __builtin_amdgcn_mfma_f32_16x16x32_bf16(af[i], bfr[j], acc[i][j], 0, 0, 0);
    }
  }

  // fused LSTM-cell epilogue
  __syncthreads();
  float* ep = (float*)smem + w * 1280;
  const int ul = lane & 3, ml = lane >> 2;
  const int ubase = (n0 >> 2) + (wn >> 2);
#pragma unroll 1
  for (int tj = 0; tj < 4; ++tj) {
#pragma unroll
    for (int ti = 0; ti < 4; ++ti)
#pragma unroll
      for (int v = 0; v < 4; ++v)
        ep[((ti << 4) + (q << 2) + v) * 20 + l15] = acc[ti][tj][v];
    __syncthreads();
#pragma unroll
    for (int p = 0; p < 4; ++p) {
      int row = ml + (p << 4);
      f32x4 z = *(const f32x4*)&ep[row * 20 + (ul << 2)];
      int gm = m0 + wm + row;
      int gu = ubase + (tj << 2) + ul;
      const f32x4 bb = *(const f32x4*)&biasp[gu << 2];
      z.x += bb.x; z.y += bb.y; z.z += bb.z; z.w += bb.w;
      if (evec) {
        float gs = escal[(size_t)gm * estride];
        const f32x4 ev = *(const f32x4*)&evec[gu << 2];
        z.x += gs * ev.x; z.y += gs * ev.y; z.z += gs * ev.z; z.w += gs * ev.w;
      }
      float ig = sigm(z.x), fg = sigm(z.y), gg = tanh_(z.z), og = sigm(z.w);
      size_t ci = ((size_t)gm << 10) + gu;
      float cn = fg * cst[ci] + ig * gg;
      cst[ci] = cn;
      hout[ci] = f2bf(og * tanh_(cn));
    }
    __syncthreads();
  }
}

// -------------------- persistent-kernel units --------------------
// heavy uid: [0,512)=d2(delay4) [512,1024)=g2(delay1) [1024,1536)=g1(delay0) [1536,2048)=d1(delay3)

__device__ __forceinline__ void do_heavy(int uid, int u, const Params& p, u16* smem) {
  const int stage = uid >> 9;
  const u16 *A0, *A1, *BT;
  int lda1 = H_, kt1 = 16, ldb = 2048, t;
  const float *bias, *evec = nullptr, *escal = nullptr;
  int estride = 0;
  float* cst; u16* hout;
  if (stage == 0) {            // d2
    t = u - 4; if (t < 0 || t >= T_) return;
    A0 = (t & 1) ? p.hd2b : p.hd2a;
    A1 = (t & 1) ? p.hd1a : p.hd1b;
    BT = p.BTd2; bias = p.pbd2; cst = p.cd2;
    hout = (t & 1) ? p.hd2a : p.hd2b;
  } else if (stage == 1) {     // g2
    t = u - 1; if (t < 0 || t >= T_) return;
    A0 = (t & 1) ? p.h2b : p.h2a;
    A1 = (t & 1) ? p.h1a : p.h1b;
    BT = p.BT2; bias = p.pb2; cst = p.c2;
    hout = (t & 1) ? p.h2a : p.h2b;
  } else if (stage == 2) {     // g1
    t = u; if (t < 0 || t >= T_) return;
    A0 = (t & 1) ? p.h1b : p.h1a;
    A1 = p.xT + (size_t)t * B_ * I_; lda1 = I_; kt1 = 1;
    BT = p.BT1; ldb = 1088; bias = p.pb1; cst = p.c1;
    hout = (t & 1) ? p.h1a : p.h1b;
  } else {                     // d1
    t = u - 3; if (t < 0 || t >= T_) return;
    A0 = (t & 1) ? p.hd1b : p.hd1a;
    A1 = nullptr; kt1 = 0;
    BT = p.BTd1; ldb = 1024; bias = p.pbd1; cst = p.cd1;
    evec = p.pd1W; escal = p.gen + t; estride = T_;
    hout = (t & 1) ? p.hd1a : p.hd1b;
  }
  gemm_body(smem, uid & 511, A0, H_, 16, A1, lda1, kt1, BT, ldb,
            bias, evec, escal, estride, cst, hout);
}

__device__ __forceinline__ void do_small(int sid, int u, const Params& p) {
  const int lane = threadIdx.x & 63;
  if (sid < 512) {             // g3: LSTM H=1 over h2[t], 4 rows/unit
    int t = u - 2; if (t < 0 || t >= T_) return;
    const u16* h2 = (t & 1) ? p.h2a : p.h2b;
    int b = sid * 4 + (threadIdx.x >> 6);
    float a0 = 0.f, a1 = 0.f, a2 = 0.f, a3 = 0.f;
    for (int k = lane; k < H_; k += 64) {
      float hv = bf2f(h2[((size_t)b << 10) + k]);
      const f32x4 wv = *(const f32x4*)&p.g3W[k << 2];
      a0 += hv * wv.x; a1 += hv * wv.y; a2 += hv * wv.z; a3 += hv * wv.w;
    }
    for (int off = 32; off; off >>= 1) {
      a0 += __shfl_down(a0, off);
      a1 += __shfl_down(a1, off);
      a2 += __shfl_down(a2, off);
      a3 += __shfl_down(a3, off);
    }
    if (lane == 0) {
      float hp = p.h3[b];
      float zi = a0 + hp * p.g3U[0] + p.g3b[0];
      float zf = a1 + hp * p.g3U[1] + p.g3b[1];
      float zg = a2 + hp * p.g3U[2] + p.g3b[2];
      float zo = a3 + hp * p.g3U[3] + p.g3b[3];
      float cn = sigm(zf) * p.c3[b] + sigm(zi) * tanh_(zg);
      p.c3[b] = cn;
      float hn = sigm(zo) * tanh_(cn);
      p.h3[b] = hn;
      p.gen[b * T_ + t] = hn;
    }
  } else {                     // dense over hd2[t]
    int t = u - 5; if (t < 0 || t >= T_) return;
    const u16* hd2 = (t & 1) ? p.hd2a : p.hd2b;
    int b = (sid - 512) * 4 + (threadIdx.x >> 6);
    float a = 0.f;
    for (int k = lane; k < H_; k += 64)
      a += bf2f(hd2[((size_t)b << 10) + k]) * p.doW[k];
    for (int off = 32; off; off >>= 1) a += __shfl_down(a, off);
    if (lane == 0) p.disc[b * T_ + t] = a + p.dob[0];
  }
}

// Device-wide barrier: monotonic counter, agent-scope fences for cross-XCD
// coherence (release -> L2 writeback to LLC; acquire -> invalidate stale L1/L2).
__device__ __forceinline__ void grid_barrier(int* cnt, int phase) {
  __syncthreads();
  if (threadIdx.x == 0) {
    __builtin_amdgcn_fence(__ATOMIC_RELEASE, "agent");
    __hip_atomic_fetch_add(cnt, 1, __ATOMIC_RELAXED, __HIP_MEMORY_SCOPE_AGENT);
    const int target = (phase + 1) * NBLK;
    while (__hip_atomic_load(cnt, __ATOMIC_RELAXED, __HIP_MEMORY_SCOPE_AGENT) < target)
      __builtin_amdgcn_s_sleep(8);
    __builtin_amdgcn_fence(__ATOMIC_ACQUIRE, "agent");
  }
  __syncthreads();
}

// -------------------- persistent kernel --------------------
// 768 blocks = 3 blocks/CU on 256 CUs (guaranteed by launch_bounds + 32KB LDS).
// Per step: block<256: d2+g2 (64 K-iters); 256..511: d2+g1+d1+2 small (65);
// 512..767: g2+g1+d1+2 small (65).
__global__ __launch_bounds__(256, 3) void k_persist(Params p) {
  __shared__ u16 smem[16384];
  const int b = blockIdx.x;
  for (int u = 0; u < T_ + 5; ++u) {
    if (b < 256) {
      do_heavy(b, u, p, smem);
      do_heavy(512 + b, u, p, smem);
    } else if (b < 512) {
      do_heavy(b, u, p, smem);
      do_heavy(1024 + (b - 256), u, p, smem);
      do_heavy(1536 + (b - 256), u, p, smem);
      do_small(2 * (b - 256), u, p);
      do_small(2 * (b - 256) + 1, u, p);
    } else {
      do_heavy(512 + (b - 256), u, p, smem);
      do_heavy(1024 + (b - 256), u, p, smem);
      do_heavy(1536 + (b - 256), u, p, smem);
      do_small(2 * (b - 256), u, p);
      do_small(2 * (b - 256) + 1, u, p);
    }
    grid_barrier(p.bcnt, u);
  }
}

// -------------------- launcher --------------------

extern "C" void kernel_launch(void* const* d_in, const int* in_sizes, int n_in,
                              void* d_out, int out_size, void* d_ws, size_t ws_size,
                              hipStream_t stream) {
  const float* x   = (const float*)d_in[0];
  const float* g1W = (const float*)d_in[1];
  const float* g1U = (const float*)d_in[2];
  const float* g1b = (const float*)d_in[3];
  const float* g2W = (const float*)d_in[4];
  const float* g2U = (const float*)d_in[5];
  const float* g2b = (const float*)d_in[6];
  const float* g3W = (const float*)d_in[7];
  const float* g3U = (const float*)d_in[8];
  const float* g3b = (const float*)d_in[9];
  const float* d1W = (const float*)d_in[10];
  const float* d1U = (const float*)d_in[11];
  const float* d1b = (const float*)d_in[12];
  const float* d2W = (const float*)d_in[13];
  const float* d2U = (const float*)d_in[14];
  const float* d2b = (const float*)d_in[15];
  const float* doW = (const float*)d_in[16];
  const float* dob = (const float*)d_in[17];

  char* ws = (char*)d_ws;
  Params p;
  p.xT   = (const u16*)(ws + 0);
  p.BT1  = (const u16*)(ws + 16777216);
  p.BT2  = (const u16*)(ws + 25690112);
  p.BTd1 = (const u16*)(ws + 42467328);
  p.BTd2 = (const u16*)(ws + 50855936);
  p.pb1  = (const float*)(ws + 67633152);
  p.pb2  = (const float*)(ws + 67649536);
  p.pbd1 = (const float*)(ws + 67665920);
  p.pbd2 = (const float*)(ws + 67682304);
  p.pd1W = (const float*)(ws + 67698688);
  const size_t Z0 = 67715072;
  p.c1  = (float*)(ws + Z0);
  p.c2  = (float*)(ws + Z0 + 8388608);
  p.cd1 = (float*)(ws + Z0 + 16777216);
  p.cd2 = (float*)(ws + Z0 + 25165824);
  p.h1a  = (u16*)(ws + Z0 + 33554432);
  p.h1b  = (u16*)(ws + Z0 + 37748736);
  p.h2a  = (u16*)(ws + Z0 + 41943040);
  p.h2b  = (u16*)(ws + Z0 + 46137344);
  p.hd1a = (u16*)(ws + Z0 + 50331648);
  p.hd1b = (u16*)(ws + Z0 + 54525952);
  p.hd2a = (u16*)(ws + Z0 + 58720256);
  p.hd2b = (u16*)(ws + Z0 + 62914560);
  p.c3 = (float*)(ws + Z0 + 67108864);
  p.h3 = (float*)(ws + Z0 + 67117056);
  p.bcnt = (int*)(ws + Z0 + 67125248);
  const size_t ZBYTES = 67125504;
  p.g3W = g3W; p.g3U = g3U; p.g3b = g3b; p.doW = doW; p.dob = dob;
  p.gen = (float*)d_out;
  p.disc = p.gen + (size_t)B_ * T_;

  k_transpose_x<<<32768, 256, 0, stream>>>(x, (u16*)p.xT);
  k_build_bt2<<<dim3(17, 64), 256, 0, stream>>>(g1U, g1W, (u16*)p.BT1, 1024, 1088);
  k_build_bt2<<<dim3(32, 64), 256, 0, stream>>>(g2U, g2W, (u16*)p.BT2, 1024, 2048);
  k_build_bt2<<<dim3(16, 64), 256, 0, stream>>>(d1U, nullptr, (u16*)p.BTd1, 1024, 1024);
  k_build_bt2<<<dim3(32, 64), 256, 0, stream>>>(d2U, d2W, (u16*)p.BTd2, 1024, 2048);
  k_build_bias<<<16, 256, 0, stream>>>(g1b, g2b, d1b, d2b, d1W,
                                       (float*)p.pb1, (float*)p.pb2, (float*)p.pbd1,
                                       (float*)p.pbd2, (float*)p.pd1W);
  (void)hipMemsetAsync(ws + Z0, 0, ZBYTES, stream);

  k_persist<<<NBLK, 256, 0, stream>>>(p);

  (void)in_sizes; (void)n_in; (void)out_size; (void)ws_size;
}

// Round 4
// 36811.526 us; speedup vs baseline: 1.5079x; 1.5079x over previous
//
#include <hip/hip_runtime.h>

typedef unsigned short u16;
typedef __attribute__((ext_vector_type(8))) short short8;
typedef __attribute__((ext_vector_type(4))) float f32x4;

#define B_ 2048
#define T_ 64
#define I_ 64
#define H_ 1024
#define G_ 4096

__device__ __forceinline__ float bf2f(u16 v) {
  union { float f; unsigned u; } x; x.u = ((unsigned)v) << 16; return x.f;
}
__device__ __forceinline__ u16 f2bf(float f) {
  union { float f; unsigned u; } x; x.f = f;
  unsigned r = x.u + 0x7fffu + ((x.u >> 16) & 1u);
  return (u16)(r >> 16);
}
__device__ __forceinline__ float sigm(float x) { return 1.0f / (1.0f + __expf(-x)); }
__device__ __forceinline__ float tanh_(float x) { return 1.0f - 2.0f / (__expf(2.0f * x) + 1.0f); }

__device__ __forceinline__ void async_copy16(const u16* g, u16* l) {
  __builtin_amdgcn_global_load_lds((__attribute__((address_space(1))) void*)(void*)g,
                                   (__attribute__((address_space(3))) void*)l, 16, 0, 0);
}

// -------------------- setup kernels --------------------

__global__ void k_transpose_x(const float* __restrict__ x, u16* __restrict__ xT) {
  int idx = blockIdx.x * 256 + threadIdx.x;
  if (idx >= B_ * T_ * I_) return;
  int i = idx & 63;
  int t = (idx >> 6) & 63;
  int b = idx >> 12;
  xT[((size_t)t * B_ + b) * I_ + i] = f2bf(x[idx]);
}

// Coalesced build of BT [4096][K] bf16 via LDS transpose.
// Row n' = 4*unit + gate; source col j = gate*1024 + unit; k<K0 from U else W.
__global__ void k_build_bt2(const float* __restrict__ U, const float* __restrict__ W,
                            u16* __restrict__ BT, int K0, int K) {
  __shared__ u16 tile[64][65];
  int k0 = blockIdx.x << 6, j0 = blockIdx.y << 6;
  int tx = threadIdx.x & 63, ty = threadIdx.x >> 6;
#pragma unroll 4
  for (int it = 0; it < 16; ++it) {
    int k = k0 + (it << 2) + ty;
    float v = (k < K0) ? U[(size_t)k * G_ + j0 + tx]
                       : W[(size_t)(k - K0) * G_ + j0 + tx];
    tile[tx][(it << 2) + ty] = f2bf(v);
  }
  __syncthreads();
#pragma unroll 4
  for (int it = 0; it < 16; ++it) {
    int j = j0 + (it << 2) + ty;
    int n = ((j & 1023) << 2) | (j >> 10);
    BT[(size_t)n * K + k0 + tx] = tile[(it << 2) + ty][tx];
  }
}

__global__ void k_build_bias(const float* __restrict__ b1, const float* __restrict__ b2,
                             const float* __restrict__ bd1, const float* __restrict__ bd2,
                             const float* __restrict__ d1W,
                             float* __restrict__ p1, float* __restrict__ p2,
                             float* __restrict__ pd1, float* __restrict__ pd2,
                             float* __restrict__ pd1W) {
  int n = blockIdx.x * 256 + threadIdx.x;
  if (n >= G_) return;
  int j = (n & 3) * 1024 + (n >> 2);
  p1[n] = b1[j]; p2[n] = b2[j]; pd1[n] = bd1[j]; pd2[n] = bd2[j];
  pd1W[n] = d1W[j];
}

// -------------------- params --------------------

struct Params {
  const u16* xT;
  const u16 *BT1, *BT2, *BTd1, *BTd2;
  const float *pb1, *pb2, *pbd1, *pbd2, *pd1W;
  float *c1, *c2, *cd1, *cd2;
  u16 *h1a, *h1b, *h2a, *h2b, *hd1a, *hd1b, *hd2a, *hd2b;
  float *c3, *h3;
  const float *g3W, *g3U, *g3b, *doW, *dob;
  float *gen, *disc;
};

// -------------------- fused GEMM + LSTM cell (device body) --------------------

__device__ __forceinline__ void gemm_body(
    u16* smem, int bid,
    const u16* __restrict__ A0, int lda0, int kt0,
    const u16* __restrict__ A1, int lda1, int kt1,
    const u16* __restrict__ BT, int ldb,
    const float* __restrict__ biasp,
    const float* __restrict__ evec,
    const float* __restrict__ escal, int estride,
    float* __restrict__ cst, u16* __restrict__ hout) {
  const int tid = threadIdx.x;
  const int lane = tid & 63;
  const int w = tid >> 6;
  const int m0 = (bid & 15) << 7;
  const int n0 = (bid >> 4) << 7;
  const int KT = kt0 + kt1;

  const int r_ = tid >> 3, c_ = tid & 7;
  const u16* pA0[4]; const u16* pA1[4]; const u16* pB[4];
#pragma unroll
  for (int s = 0; s < 4; ++s) {
    int rs = (s << 5) + r_;
    int ch = (c_ ^ (rs & 7)) << 3;
    pA0[s] = A0 + (size_t)(m0 + rs) * lda0 + ch;
    pA1[s] = A1 ? (A1 + (size_t)(m0 + rs) * lda1 + ch) : pA0[s];
    pB[s] = BT + (size_t)(n0 + rs) * ldb + ch;
  }
  u16* ldsA = smem + (w << 9);
  u16* ldsB = smem + 8192 + (w << 9);

  f32x4 acc[4][4];
#pragma unroll
  for (int i = 0; i < 4; ++i)
#pragma unroll
    for (int j = 0; j < 4; ++j) acc[i][j] = (f32x4){0.f, 0.f, 0.f, 0.f};

  const int wm = (w >> 1) << 6, wn = (w & 1) << 6;
  const int q = lane >> 4, l15 = lane & 15, l7 = lane & 7;
  int aoffr[4], boffr[4];
#pragma unroll
  for (int i = 0; i < 4; ++i) {
    aoffr[i] = (wm + (i << 4) + l15) << 6;
    boffr[i] = 8192 + ((wn + (i << 4) + l15) << 6);
  }

  for (int kt = 0; kt < KT; ++kt) {
    __syncthreads();
    bool seg0 = (kt < kt0);
#pragma unroll
    for (int s = 0; s < 4; ++s) {
      const u16* ga = seg0 ? (pA0[s] + (size_t)kt * 64)
                           : (pA1[s] + (size_t)(kt - kt0) * 64);
      async_copy16(ga, ldsA + (s << 11));
      async_copy16(pB[s] + (size_t)kt * 64, ldsB + (s << 11));
    }
    __syncthreads();
#pragma unroll
    for (int ks = 0; ks < 2; ++ks) {
      const int sw = ((((ks << 2) + q) ^ l7) << 3);
      short8 af[4], bfr[4];
#pragma unroll
      for (int i = 0; i < 4; ++i) {
        af[i] = *(const short8*)&smem[aoffr[i] + sw];
        bfr[i] = *(const short8*)&smem[boffr[i] + sw];
      }
#pragma unroll
      for (int i = 0; i < 4; ++i)
#pragma unroll
        for (int j = 0; j < 4; ++j)
          acc[i][j] = __builtin_amdgcn_mfma_f32_16x16x32_bf16(af[i], bfr[j], acc[i][j], 0, 0, 0);
    }
  }

  // fused LSTM-cell epilogue
  __syncthreads();
  float* ep = (float*)smem + w * 1280;
  const int ul = lane & 3, ml = lane >> 2;
  const int ubase = (n0 >> 2) + (wn >> 2);
#pragma unroll 1
  for (int tj = 0; tj < 4; ++tj) {
#pragma unroll
    for (int ti = 0; ti < 4; ++ti)
#pragma unroll
      for (int v = 0; v < 4; ++v)
        ep[((ti << 4) + (q << 2) + v) * 20 + l15] = acc[ti][tj][v];
    __syncthreads();
#pragma unroll
    for (int p = 0; p < 4; ++p) {
      int row = ml + (p << 4);
      f32x4 z = *(const f32x4*)&ep[row * 20 + (ul << 2)];
      int gm = m0 + wm + row;
      int gu = ubase + (tj << 2) + ul;
      const f32x4 bb = *(const f32x4*)&biasp[gu << 2];
      z.x += bb.x; z.y += bb.y; z.z += bb.z; z.w += bb.w;
      if (evec) {
        float gs = escal[(size_t)gm * estride];
        const f32x4 ev = *(const f32x4*)&evec[gu << 2];
        z.x += gs * ev.x; z.y += gs * ev.y; z.z += gs * ev.z; z.w += gs * ev.w;
      }
      float ig = sigm(z.x), fg = sigm(z.y), gg = tanh_(z.z), og = sigm(z.w);
      size_t ci = ((size_t)gm << 10) + gu;
      float cn = fg * cst[ci] + ig * gg;
      cst[ci] = cn;
      hout[ci] = f2bf(og * tanh_(cn));
    }
    __syncthreads();
  }
}

// -------------------- fused wavefront kernel --------------------
// wavefront u runs: g1[u], g2[u-1], g3[u-2], d1[u-3], d2[u-4], dense[u-5].
// XCD-locality swizzle: HW assigns XCD ~ blockIdx.x % 8. Map the 512 blocks of
// each GEMM stage so one XCD owns 4 n-tiles (B working set 4x512KB = 2MB <= 4MB
// L2): nt = (b&7) + 8*((b>>3)&3), mt = b>>5. B is then fetched once per XCD
// per step and L2-hit by the other 15 m-blocks.
__global__ __launch_bounds__(256, 3)
void k_fused(int u, Params p) {
  __shared__ u16 smem[16384];
  const int blk = blockIdx.x;

  if (blk < 2048) {
    const u16 *A0, *A1, *BT;
    int lda0 = H_, lda1 = H_, kt0 = 16, kt1 = 16, ldb = 2048;
    const float *bias, *evec = nullptr, *escal = nullptr;
    int estride = 0, t;
    float* cst; u16* hout;
    if (blk < 512) {            // d2: z = hd2[t-1]@U + hd1[t]@W
      t = u - 4; if (t < 0 || t >= T_) return;
      A0 = (t & 1) ? p.hd2b : p.hd2a;
      A1 = (t & 1) ? p.hd1a : p.hd1b;
      BT = p.BTd2; bias = p.pbd2; cst = p.cd2;
      hout = (t & 1) ? p.hd2a : p.hd2b;
    } else if (blk < 1024) {    // g2: z = h2[t-1]@U + h1[t]@W
      t = u - 1; if (t < 0 || t >= T_) return;
      A0 = (t & 1) ? p.h2b : p.h2a;
      A1 = (t & 1) ? p.h1a : p.h1b;
      BT = p.BT2; bias = p.pb2; cst = p.c2;
      hout = (t & 1) ? p.h2a : p.h2b;
    } else if (blk < 1536) {    // g1: z = h1[t-1]@U + x_t@W
      t = u; if (t < 0 || t >= T_) return;
      A0 = (t & 1) ? p.h1b : p.h1a;
      A1 = p.xT + (size_t)t * B_ * I_; lda1 = I_; kt1 = 1;
      BT = p.BT1; ldb = 1088; bias = p.pb1; cst = p.c1;
      hout = (t & 1) ? p.h1a : p.h1b;
    } else {                    // d1: z = hd1[t-1]@U (+ gen_t*d1W in epilogue)
      t = u - 3; if (t < 0 || t >= T_) return;
      A0 = (t & 1) ? p.hd1b : p.hd1a;
      A1 = nullptr; kt1 = 0;
      BT = p.BTd1; ldb = 1024; bias = p.pbd1; cst = p.cd1;
      evec = p.pd1W; escal = p.gen + t; estride = T_;
      hout = (t & 1) ? p.hd1a : p.hd1b;
    }
    const int b5 = blk & 511;
    const int nt = (b5 & 7) + (((b5 >> 3) & 3) << 3);
    const int mt = b5 >> 5;
    gemm_body(smem, mt | (nt << 4), A0, lda0, kt0, A1, lda1, kt1, BT, ldb,
              bias, evec, escal, estride, cst, hout);
    return;
  }

  const int lane = threadIdx.x & 63;
  if (blk < 2560) {             // g3: LSTM H=1 over h2[t]
    int t = u - 2; if (t < 0 || t >= T_) return;
    const u16* h2 = (t & 1) ? p.h2a : p.h2b;
    int b = (blk - 2048) * 4 + (threadIdx.x >> 6);
    float a0 = 0.f, a1 = 0.f, a2 = 0.f, a3 = 0.f;
    for (int k = lane; k < H_; k += 64) {
      float hv = bf2f(h2[((size_t)b << 10) + k]);
      const f32x4 wv = *(const f32x4*)&p.g3W[k << 2];
      a0 += hv * wv.x; a1 += hv * wv.y; a2 += hv * wv.z; a3 += hv * wv.w;
    }
    for (int off = 32; off; off >>= 1) {
      a0 += __shfl_down(a0, off);
      a1 += __shfl_down(a1, off);
      a2 += __shfl_down(a2, off);
      a3 += __shfl_down(a3, off);
    }
    if (lane == 0) {
      float hp = p.h3[b];
      float zi = a0 + hp * p.g3U[0] + p.g3b[0];
      float zf = a1 + hp * p.g3U[1] + p.g3b[1];
      float zg = a2 + hp * p.g3U[2] + p.g3b[2];
      float zo = a3 + hp * p.g3U[3] + p.g3b[3];
      float cn = sigm(zf) * p.c3[b] + sigm(zi) * tanh_(zg);
      p.c3[b] = cn;
      float hn = sigm(zo) * tanh_(cn);
      p.h3[b] = hn;
      p.gen[b * T_ + t] = hn;
    }
  } else {                      // dense over hd2[t]
    int t = u - 5; if (t < 0 || t >= T_) return;
    const u16* hd2 = (t & 1) ? p.hd2a : p.hd2b;
    int b = (blk - 2560) * 4 + (threadIdx.x >> 6);
    float a = 0.f;
    for (int k = lane; k < H_; k += 64)
      a += bf2f(hd2[((size_t)b << 10) + k]) * p.doW[k];
    for (int off = 32; off; off >>= 1) a += __shfl_down(a, off);
    if (lane == 0) p.disc[b * T_ + t] = a + p.dob[0];
  }
}

// -------------------- launcher --------------------

extern "C" void kernel_launch(void* const* d_in, const int* in_sizes, int n_in,
                              void* d_out, int out_size, void* d_ws, size_t ws_size,
                              hipStream_t stream) {
  const float* x   = (const float*)d_in[0];
  const float* g1W = (const float*)d_in[1];
  const float* g1U = (const float*)d_in[2];
  const float* g1b = (const float*)d_in[3];
  const float* g2W = (const float*)d_in[4];
  const float* g2U = (const float*)d_in[5];
  const float* g2b = (const float*)d_in[6];
  const float* g3W = (const float*)d_in[7];
  const float* g3U = (const float*)d_in[8];
  const float* g3b = (const float*)d_in[9];
  const float* d1W = (const float*)d_in[10];
  const float* d1U = (const float*)d_in[11];
  const float* d1b = (const float*)d_in[12];
  const float* d2W = (const float*)d_in[13];
  const float* d2U = (const float*)d_in[14];
  const float* d2b = (const float*)d_in[15];
  const float* doW = (const float*)d_in[16];
  const float* dob = (const float*)d_in[17];

  char* ws = (char*)d_ws;
  Params p;
  p.xT   = (const u16*)(ws + 0);
  p.BT1  = (const u16*)(ws + 16777216);
  p.BT2  = (const u16*)(ws + 25690112);
  p.BTd1 = (const u16*)(ws + 42467328);
  p.BTd2 = (const u16*)(ws + 50855936);
  p.pb1  = (const float*)(ws + 67633152);
  p.pb2  = (const float*)(ws + 67649536);
  p.pbd1 = (const float*)(ws + 67665920);
  p.pbd2 = (const float*)(ws + 67682304);
  p.pd1W = (const float*)(ws + 67698688);
  const size_t Z0 = 67715072;
  p.c1  = (float*)(ws + Z0);
  p.c2  = (float*)(ws + Z0 + 8388608);
  p.cd1 = (float*)(ws + Z0 + 16777216);
  p.cd2 = (float*)(ws + Z0 + 25165824);
  p.h1a  = (u16*)(ws + Z0 + 33554432);
  p.h1b  = (u16*)(ws + Z0 + 37748736);
  p.h2a  = (u16*)(ws + Z0 + 41943040);
  p.h2b  = (u16*)(ws + Z0 + 46137344);
  p.hd1a = (u16*)(ws + Z0 + 50331648);
  p.hd1b = (u16*)(ws + Z0 + 54525952);
  p.hd2a = (u16*)(ws + Z0 + 58720256);
  p.hd2b = (u16*)(ws + Z0 + 62914560);
  p.c3 = (float*)(ws + Z0 + 67108864);
  p.h3 = (float*)(ws + Z0 + 67117056);
  const size_t ZBYTES = 67125248;
  p.g3W = g3W; p.g3U = g3U; p.g3b = g3b; p.doW = doW; p.dob = dob;
  p.gen = (float*)d_out;
  p.disc = p.gen + (size_t)B_ * T_;

  k_transpose_x<<<32768, 256, 0, stream>>>(x, (u16*)p.xT);
  k_build_bt2<<<dim3(17, 64), 256, 0, stream>>>(g1U, g1W, (u16*)p.BT1, 1024, 1088);
  k_build_bt2<<<dim3(32, 64), 256, 0, stream>>>(g2U, g2W, (u16*)p.BT2, 1024, 2048);
  k_build_bt2<<<dim3(16, 64), 256, 0, stream>>>(d1U, nullptr, (u16*)p.BTd1, 1024, 1024);
  k_build_bt2<<<dim3(32, 64), 256, 0, stream>>>(d2U, d2W, (u16*)p.BTd2, 1024, 2048);
  k_build_bias<<<16, 256, 0, stream>>>(g1b, g2b, d1b, d2b, d1W,
                                       (float*)p.pb1, (float*)p.pb2, (float*)p.pbd1,
                                       (float*)p.pbd2, (float*)p.pd1W);
  (void)hipMemsetAsync(ws + Z0, 0, ZBYTES, stream);

  for (int u = 0; u < T_ + 5; ++u)
    k_fused<<<3072, 256, 0, stream>>>(u, p);

  (void)in_sizes; (void)n_in; (void)out_size; (void)ws_size;
}